// Round 2
// baseline (109.530 us; speedup 1.0000x reference)
//
#include <hip/hip_runtime.h>
#include <hip/hip_fp16.h>

typedef __attribute__((ext_vector_type(8))) _Float16 f16x8;
typedef __attribute__((ext_vector_type(4))) float f32x4;
typedef __attribute__((ext_vector_type(2))) float f32x2;
typedef __attribute__((ext_vector_type(2))) __fp16 fp16x2;

__device__ inline unsigned int pack_f16(float x, float y) {
    union { fp16x2 h; unsigned int u; } c;
    c.h = __builtin_amdgcn_cvt_pkrtz(x, y);
    return c.u;
}
__device__ inline float2 unpack_f16(unsigned int u) {
    union { unsigned int u32; __half2 h2; } c; c.u32 = u;
    return __half22float2(c.h2);
}

// ---------------------------------------------------------------------------
// Kernel 0 (grid 224): bid<128: transpose+cvt W -> WT16[u][d] fp16.
//                      bid 128..191: enc fp32 -> fp16.  192..223: dec -> fp16.
// (enc16/dec16 are consumed only by proj_kernel now; attend reads enc fp32.)
// ---------------------------------------------------------------------------
__global__ __launch_bounds__(256) void prep_w(
    const float* __restrict__ Wenc, const float* __restrict__ Wdec,
    const float* __restrict__ enc,  const float* __restrict__ dec,
    unsigned short* __restrict__ WeT, unsigned short* __restrict__ WdT,
    unsigned short* __restrict__ enc16, unsigned short* __restrict__ dec16)
{
    __shared__ float L[64][65];
    const int bid = blockIdx.x;
    const int t = threadIdx.x;
    if (bid >= 128) {                    // fp32 -> fp16 bulk convert
        const float* src; unsigned int* dst;
        if (bid < 192) { int blk = bid - 128; src = enc + (size_t)blk * 16384;
                         dst = (unsigned int*)enc16 + (size_t)blk * 8192; }
        else           { int blk = bid - 192; src = dec + (size_t)blk * 16384;
                         dst = (unsigned int*)dec16 + (size_t)blk * 8192; }
#pragma unroll 4
        for (int i = 0; i < 16; ++i) {
            int off = (i << 10) + (t << 2);
            float4 v = *(const float4*)(src + off);
            *(uint2*)(dst + (off >> 1)) =
                make_uint2(pack_f16(v.x, v.y), pack_f16(v.z, v.w));
        }
        return;
    }
    const float* W = (bid < 64) ? Wenc : Wdec;
    unsigned short* T = (bid < 64) ? WeT : WdT;
    const int tb = bid & 63;
    const int d0 = (tb >> 3) << 6, u0v = (tb & 7) << 6;
    {
        const int c4 = (t & 15) << 2;
#pragma unroll
        for (int i = 0; i < 4; ++i) {
            int row = (i << 4) + (t >> 4);
            float4 v = *(const float4*)&W[(size_t)(d0 + row) * 512 + u0v + c4];
            L[row][c4 + 0] = v.x;
            L[row][c4 + 1] = v.y;
            L[row][c4 + 2] = v.z;
            L[row][c4 + 3] = v.w;
        }
    }
    __syncthreads();
    const int u = t >> 2, dg = t & 3;
    unsigned int hw[8];
#pragma unroll
    for (int j = 0; j < 8; ++j) {
        float x0 = L[(dg << 4) + (j << 1) + 0][u];
        float x1 = L[(dg << 4) + (j << 1) + 1][u];
        hw[j] = pack_f16(x0, x1);
    }
    size_t ob = (size_t)(u0v + u) * 512 + d0 + (dg << 4);
    *(uint4*)&T[ob]     = make_uint4(hw[0], hw[1], hw[2], hw[3]);
    *(uint4*)&T[ob + 8] = make_uint4(hw[4], hw[5], hw[6], hw[7]);
}

// ---------------------------------------------------------------------------
// Kernel 1 (grid 768, 128 thr = 2 waves): fp16 MFMA projections, no LDS,
// 8-deep register pipeline (128 stage VGPRs; ~170 total, no spill at (128,1)).
// 8-deep covers ~28 MFMAs (~150-200 cyc) between load issue and use -> hides
// L2 latency at 1.5 waves/SIMD.  Second half-loop issues NO prefetch (the old
// 4-deep wrapped tail wasted 25% dead loads).
//   bid<512 : enc proj, rows=u cols=e. Epilogue: EH = exp2((d_enc+b)*2log2e)
//             fp16, u-packed-by-4.
//   bid>=512: dec proj, rows=q cols=u. Epilogue:
//             Gq4[b][q>>2][u][q&3] = exp2((dd+b)*2log2e) fp32 (q-packed).
// ---------------------------------------------------------------------------
__global__ __launch_bounds__(128, 1) void proj_kernel(
    const unsigned short* __restrict__ enc16, const unsigned short* __restrict__ dec16,
    const unsigned short* __restrict__ WeT,   const unsigned short* __restrict__ WdT,
    const float* __restrict__ bias_enc, const float* __restrict__ bias_dec,
    unsigned short* __restrict__ EH,   // [B][128][256][4] fp16
    float* __restrict__ Gq4)           // [B][32][512][4] fp32
{
    const float Cs = 2.8853900817779268f;   // 2*log2(e)
    const int bid = blockIdx.x;
    const int t = threadIdx.x;
    const int lane = t & 63, wr = t >> 6;    // wr: 32-row half of 64-row tile
    const int frow = lane & 15, quad = lane >> 4;
    const int ko = quad << 3;

    const unsigned short *pa0, *pa1, *pb0, *pb1;
    if (bid < 512) {
        const int b = bid & 7, s = bid >> 3;
        const int u0 = ((s & 7) << 6) + (wr << 5);   // 8 u-tiles of 64
        const int e0 = (s >> 3) << 5;                // 8 e-tiles of 32
        pa0 = WeT + (size_t)(u0 + frow) * 512 + ko;
        pa1 = pa0 + 16 * 512;
        pb0 = enc16 + (size_t)((b << 8) + e0 + frow) * 512 + ko;
        pb1 = pb0 + 16 * 512;
    } else {
        const int s = bid - 512;
        const int b = s & 7, s2 = s >> 3;
        const int q0 = ((s2 >> 4) << 6) + (wr << 5); // 2 q-tiles of 64
        const int u0 = (s2 & 15) << 5;               // 16 u-tiles of 32
        pa0 = dec16 + (size_t)((b << 7) + q0 + frow) * 512 + ko;
        pa1 = pa0 + 16 * 512;
        pb0 = WdT + (size_t)(u0 + frow) * 512 + ko;
        pb1 = pb0 + 16 * 512;
    }

    f16x8 sa0[8], sa1[8], sb0[8], sb1[8];
    auto LD = [&](int st, int k) {
        sa0[st] = *(const f16x8*)(pa0 + k);
        sa1[st] = *(const f16x8*)(pa1 + k);
        sb0[st] = *(const f16x8*)(pb0 + k);
        sb1[st] = *(const f16x8*)(pb1 + k);
    };
    f32x4 acc[2][2] = {{{0.f,0.f,0.f,0.f},{0.f,0.f,0.f,0.f}},
                       {{0.f,0.f,0.f,0.f},{0.f,0.f,0.f,0.f}}};
#pragma unroll
    for (int st = 0; st < 8; ++st) LD(st, st << 5);
#pragma unroll
    for (int st = 0; st < 8; ++st) {
        acc[0][0] = __builtin_amdgcn_mfma_f32_16x16x32_f16(sa0[st], sb0[st], acc[0][0], 0, 0, 0);
        acc[0][1] = __builtin_amdgcn_mfma_f32_16x16x32_f16(sa0[st], sb1[st], acc[0][1], 0, 0, 0);
        acc[1][0] = __builtin_amdgcn_mfma_f32_16x16x32_f16(sa1[st], sb0[st], acc[1][0], 0, 0, 0);
        acc[1][1] = __builtin_amdgcn_mfma_f32_16x16x32_f16(sa1[st], sb1[st], acc[1][1], 0, 0, 0);
        LD(st, 256 + (st << 5));             // prefetch second K-half
    }
#pragma unroll
    for (int st = 0; st < 8; ++st) {
        acc[0][0] = __builtin_amdgcn_mfma_f32_16x16x32_f16(sa0[st], sb0[st], acc[0][0], 0, 0, 0);
        acc[0][1] = __builtin_amdgcn_mfma_f32_16x16x32_f16(sa0[st], sb1[st], acc[0][1], 0, 0, 0);
        acc[1][0] = __builtin_amdgcn_mfma_f32_16x16x32_f16(sa1[st], sb0[st], acc[1][0], 0, 0, 0);
        acc[1][1] = __builtin_amdgcn_mfma_f32_16x16x32_f16(sa1[st], sb1[st], acc[1][1], 0, 0, 0);
    }

    // epilogue (C/D: col = lane&15 -> B-row, row = quad*4 + reg -> A-row)
    if (bid < 512) {
        const int b = bid & 7, s = bid >> 3;
        const int u0 = ((s & 7) << 6) + (wr << 5);
        const int e0 = (s >> 3) << 5;
#pragma unroll
        for (int fm = 0; fm < 2; ++fm)
#pragma unroll
            for (int fn = 0; fn < 2; ++fn) {
                int ub = u0 + (fm << 4) + (quad << 2);
                int e  = e0 + (fn << 4) + frow;
                float4 bi = *(const float4*)&bias_enc[ub];
                float E0 = __builtin_amdgcn_exp2f((acc[fm][fn][0] + bi.x) * Cs);
                float E1 = __builtin_amdgcn_exp2f((acc[fm][fn][1] + bi.y) * Cs);
                float E2 = __builtin_amdgcn_exp2f((acc[fm][fn][2] + bi.z) * Cs);
                float E3 = __builtin_amdgcn_exp2f((acc[fm][fn][3] + bi.w) * Cs);
                ((uint2*)EH)[(((size_t)(b << 7) + (ub >> 2)) << 8) + e] =
                    make_uint2(pack_f16(E0, E1), pack_f16(E2, E3));
            }
    } else {
        const int s = bid - 512;
        const int b = s & 7, s2 = s >> 3;
        const int q0 = ((s2 >> 4) << 6) + (wr << 5);
        const int u0 = (s2 & 15) << 5;
#pragma unroll
        for (int fm = 0; fm < 2; ++fm)
#pragma unroll
            for (int fn = 0; fn < 2; ++fn) {
                int qb = q0 + (fm << 4) + (quad << 2);   // multiple of 4
                int u  = u0 + (fn << 4) + frow;
                float bi = bias_dec[u];
                size_t base = (((size_t)(b << 5) + (qb >> 2)) << 11) + (u << 2);
#pragma unroll
                for (int g = 0; g < 4; ++g)
                    Gq4[base + g] =
                        __builtin_amdgcn_exp2f((acc[fm][fn][g] + bi) * Cs);
            }
    }
}

// ---------------------------------------------------------------------------
// Kernel 2 (grid 256, 1024 thr, q=4/block): scores -> softmax -> context.
// Score loop: 4-way rational combining (exact algebra):
//   sum_i w_i/X_i = [(w0*Y+w1*X)*ZW + (w2*W+w3*Z)*XY] * rcp(XY*ZW)
// -> 1 v_rcp per 4 u-terms.  q-columns as two f32x2 pairs (v_pk_* halves
// issue count; pk fp32 is half-rate on gfx950 so FLOP-neutral).
// Context phase reads enc fp32 directly (no unpack, better precision).
// __launch_bounds__(1024,4): 128-reg cap, no spill.
// ---------------------------------------------------------------------------
__global__ __launch_bounds__(1024, 4) void attend_kernel(
    const float* __restrict__ enc32,           // [B,256,512] fp32
    const unsigned short* __restrict__ EH,     // [B][128][256][4] fp16
    const float* __restrict__ Gq4,             // [B][32][512][4] fp32
    const float* __restrict__ Wscore,          // [512]
    float* __restrict__ out)                   // [B, 128, 512]
{
    __shared__ float smem[8192];         // score accs 16 KB / ctx partials 32 KB
    __shared__ float wT[256][4];         // softmax weights [e][q]

    const float LOG2E = 1.4426950408889634f;

    const int bid = blockIdx.x;
    const int b = bid & 7;               // XCD-local batch
    const int qt = (bid >> 3) & 31;
    const int q0 = qt << 2;
    const int tid = threadIdx.x;
    const int wv = tid >> 6, lane = tid & 63;

    // ---------------- scores ----------------
    const int e  = ((wv & 3) << 6) + lane;
    const int uq = wv >> 2;
    const int u0 = __builtin_amdgcn_readfirstlane(uq << 7);   // SGPR-pinned

    const uint2* Ep = (const uint2*)EH + (((size_t)(b << 7) + (u0 >> 2)) << 8) + e;
    const float* Gq = Gq4 + (((size_t)(b << 5) + qt) << 11);  // [512][4]
    const float* Wp = Wscore + u0;

    f32x2 accLo = {0.f, 0.f}, accHi = {0.f, 0.f};
    uint2 de = Ep[0];
    float4 g0 = *(const float4*)(Gq + ((u0 + 0) << 2));
    float4 g1 = *(const float4*)(Gq + ((u0 + 1) << 2));
    float4 g2 = *(const float4*)(Gq + ((u0 + 2) << 2));
    float4 g3 = *(const float4*)(Gq + ((u0 + 3) << 2));
    float4 w4 = *(const float4*)(Wp);
    for (int g = 0; g < 32; ++g) {
        uint2 cde = de;
        float4 cg0 = g0, cg1 = g1, cg2 = g2, cg3 = g3, cw = w4;
        if (g < 31) {
            int un = u0 + ((g + 1) << 2);
            de = Ep[(size_t)(g + 1) << 8];
            g0 = *(const float4*)(Gq + ((un + 0) << 2));
            g1 = *(const float4*)(Gq + ((un + 1) << 2));
            g2 = *(const float4*)(Gq + ((un + 2) << 2));
            g3 = *(const float4*)(Gq + ((un + 3) << 2));
            w4 = *(const float4*)(Wp + ((g + 1) << 2));
        }
        float2 f01 = unpack_f16(cde.x);
        float2 f23 = unpack_f16(cde.y);
        const float E0 = f01.x, E1 = f01.y, E2 = f23.x, E3 = f23.y;
        // q-pair lo = (q0, q1)
        {
            f32x2 gl0 = {cg0.x, cg0.y}, gl1 = {cg1.x, cg1.y};
            f32x2 gl2 = {cg2.x, cg2.y}, gl3 = {cg3.x, cg3.y};
            f32x2 X = E0 * gl0 + 1.0f;
            f32x2 Y = E1 * gl1 + 1.0f;
            f32x2 Z = E2 * gl2 + 1.0f;
            f32x2 V = E3 * gl3 + 1.0f;
            f32x2 pxy = X * Y, pzw = Z * V;
            f32x2 den = pxy * pzw;
            f32x2 nxy = cw.x * Y + cw.y * X;
            f32x2 nzw = cw.z * V + cw.w * Z;
            f32x2 num = nxy * pzw + nzw * pxy;
            f32x2 r = { __builtin_amdgcn_rcpf(den.x),
                        __builtin_amdgcn_rcpf(den.y) };
            accLo += num * r;
        }
        // q-pair hi = (q2, q3)
        {
            f32x2 gh0 = {cg0.z, cg0.w}, gh1 = {cg1.z, cg1.w};
            f32x2 gh2 = {cg2.z, cg2.w}, gh3 = {cg3.z, cg3.w};
            f32x2 X = E0 * gh0 + 1.0f;
            f32x2 Y = E1 * gh1 + 1.0f;
            f32x2 Z = E2 * gh2 + 1.0f;
            f32x2 V = E3 * gh3 + 1.0f;
            f32x2 pxy = X * Y, pzw = Z * V;
            f32x2 den = pxy * pzw;
            f32x2 nxy = cw.x * Y + cw.y * X;
            f32x2 nzw = cw.z * V + cw.w * Z;
            f32x2 num = nxy * pzw + nzw * pxy;
            f32x2 r = { __builtin_amdgcn_rcpf(den.x),
                        __builtin_amdgcn_rcpf(den.y) };
            accHi += num * r;
        }
    }
    smem[((uq << 2) + 0) * 256 + e] = accLo.x;
    smem[((uq << 2) + 1) * 256 + e] = accLo.y;
    smem[((uq << 2) + 2) * 256 + e] = accHi.x;
    smem[((uq << 2) + 3) * 256 + e] = accHi.y;
    __syncthreads();

    // ---------------- softmax over e per q ----------------
    if (wv < 4) {
        const int q = wv;
        float l[4];
        float m = -1e30f;
#pragma unroll
        for (int i = 0; i < 4; ++i) {
            int ee = lane + (i << 6);
            float a = smem[(0 + q) * 256 + ee] + smem[(4 + q) * 256 + ee] +
                      smem[(8 + q) * 256 + ee] + smem[(12 + q) * 256 + ee];
            l[i] = -2.f * a;
            m = fmaxf(m, l[i]);
        }
#pragma unroll
        for (int mk = 32; mk >= 1; mk >>= 1) m = fmaxf(m, __shfl_xor(m, mk, 64));
        float p[4];
        float ssum = 0.f;
#pragma unroll
        for (int i = 0; i < 4; ++i) {
            p[i] = __builtin_amdgcn_exp2f((l[i] - m) * LOG2E);
            ssum += p[i];
        }
#pragma unroll
        for (int mk = 32; mk >= 1; mk >>= 1) ssum += __shfl_xor(ssum, mk, 64);
        float inv = __builtin_amdgcn_rcpf(ssum);
#pragma unroll
        for (int i = 0; i < 4; ++i) wT[lane + (i << 6)][q] = p[i] * inv;
    }
    __syncthreads();

    // ---------------- context (fp32 enc direct, LDS reduce, pk-f32) --------
    {
        const int dp = tid & 255;                // d-pair index
        f32x2 p0 = {0.f, 0.f}, p1 = {0.f, 0.f};
        f32x2 p2 = {0.f, 0.f}, p3 = {0.f, 0.f};
        const float2* ep = (const float2*)enc32 +
                           (((size_t)(b << 8) + (uq << 6)) << 8) + dp;
#pragma unroll 4
        for (int ee = 0; ee < 64; ++ee) {
            float2 xf = ep[(size_t)ee << 8];
            f32x2 x = {xf.x, xf.y};
            float4 w = *(const float4*)&wT[(uq << 6) + ee][0];   // wave-uniform
            p0 += w.x * x;
            p1 += w.y * x;
            p2 += w.z * x;
            p3 += w.w * x;
        }
        float2* sc = (float2*)smem;              // [16][256] float2 = 32 KB
        sc[((uq << 2) + 0) * 256 + dp] = make_float2(p0.x, p0.y);
        sc[((uq << 2) + 1) * 256 + dp] = make_float2(p1.x, p1.y);
        sc[((uq << 2) + 2) * 256 + dp] = make_float2(p2.x, p2.y);
        sc[((uq << 2) + 3) * 256 + dp] = make_float2(p3.x, p3.y);
        __syncthreads();
        const int q = tid >> 8;                  // 0..3
        float2 s0 = sc[(0 + q) * 256 + dp];
        float2 s1 = sc[(4 + q) * 256 + dp];
        float2 s2 = sc[(8 + q) * 256 + dp];
        float2 s3 = sc[(12 + q) * 256 + dp];
        float2 o = make_float2(s0.x + s1.x + s2.x + s3.x,
                               s0.y + s1.y + s2.y + s3.y);
        *(float2*)&out[(size_t)((b << 7) + q0 + q) * 512 + (dp << 1)] = o;
    }
}

// ---------------------------------------------------------------------------
extern "C" void kernel_launch(void* const* d_in, const int* in_sizes, int n_in,
                              void* d_out, int out_size, void* d_ws, size_t ws_size,
                              hipStream_t stream) {
    const float* enc      = (const float*)d_in[0];
    const float* dec      = (const float*)d_in[1];
    const float* Wenc     = (const float*)d_in[2];
    const float* Wdec     = (const float*)d_in[3];
    const float* Wscore   = (const float*)d_in[4];
    const float* bias_enc = (const float*)d_in[5];
    const float* bias_dec = (const float*)d_in[6];
    // d_in[7] = bias_score: constant shift, cancelled by softmax.
    float* out = (float*)d_out;

    float* ws = (float*)d_ws;
    unsigned short* EH  = (unsigned short*)ws;             // 2 MB  (1M fp16)
    float* Gq4          = ws + 524288;                     // 2 MB  (512K fp32)
    unsigned short* WeT = (unsigned short*)(ws + 1048576); // 512 KB
    unsigned short* WdT = WeT + 262144;                    // 512 KB
    unsigned short* enc16 = WdT + 262144;                  // 2 MB
    unsigned short* dec16 = enc16 + 1048576;               // 1 MB   (total 8 MB)

    prep_w<<<224, 256, 0, stream>>>(Wenc, Wdec, enc, dec, WeT, WdT, enc16, dec16);
    proj_kernel<<<768, 128, 0, stream>>>(enc16, dec16, WeT, WdT,
                                         bias_enc, bias_dec, EH, Gq4);
    attend_kernel<<<256, 1024, 0, stream>>>(enc, EH, Gq4, Wscore, out);
}

// Round 3
// 105.884 us; speedup vs baseline: 1.0344x; 1.0344x over previous
//
#include <hip/hip_runtime.h>
#include <hip/hip_fp16.h>

typedef __attribute__((ext_vector_type(8))) _Float16 f16x8;
typedef __attribute__((ext_vector_type(4))) float f32x4;
typedef __attribute__((ext_vector_type(2))) float f32x2;
typedef __attribute__((ext_vector_type(2))) __fp16 fp16x2;

__device__ inline unsigned int pack_f16(float x, float y) {
    union { fp16x2 h; unsigned int u; } c;
    c.h = __builtin_amdgcn_cvt_pkrtz(x, y);
    return c.u;
}
__device__ inline float2 unpack_f16(unsigned int u) {
    union { unsigned int u32; __half2 h2; } c; c.u32 = u;
    return __half22float2(c.h2);
}

// ---------------------------------------------------------------------------
// Kernel 0 (grid 224): bid<128: transpose+cvt W -> WT16[u][d] fp16.
//                      bid 128..191: enc fp32 -> fp16.  192..223: dec -> fp16.
// ---------------------------------------------------------------------------
__global__ __launch_bounds__(256) void prep_w(
    const float* __restrict__ Wenc, const float* __restrict__ Wdec,
    const float* __restrict__ enc,  const float* __restrict__ dec,
    unsigned short* __restrict__ WeT, unsigned short* __restrict__ WdT,
    unsigned short* __restrict__ enc16, unsigned short* __restrict__ dec16)
{
    __shared__ float L[64][65];
    const int bid = blockIdx.x;
    const int t = threadIdx.x;
    if (bid >= 128) {                    // fp32 -> fp16 bulk convert
        const float* src; unsigned int* dst;
        if (bid < 192) { int blk = bid - 128; src = enc + (size_t)blk * 16384;
                         dst = (unsigned int*)enc16 + (size_t)blk * 8192; }
        else           { int blk = bid - 192; src = dec + (size_t)blk * 16384;
                         dst = (unsigned int*)dec16 + (size_t)blk * 8192; }
#pragma unroll 4
        for (int i = 0; i < 16; ++i) {
            int off = (i << 10) + (t << 2);
            float4 v = *(const float4*)(src + off);
            *(uint2*)(dst + (off >> 1)) =
                make_uint2(pack_f16(v.x, v.y), pack_f16(v.z, v.w));
        }
        return;
    }
    const float* W = (bid < 64) ? Wenc : Wdec;
    unsigned short* T = (bid < 64) ? WeT : WdT;
    const int tb = bid & 63;
    const int d0 = (tb >> 3) << 6, u0v = (tb & 7) << 6;
    {
        const int c4 = (t & 15) << 2;
#pragma unroll
        for (int i = 0; i < 4; ++i) {
            int row = (i << 4) + (t >> 4);
            float4 v = *(const float4*)&W[(size_t)(d0 + row) * 512 + u0v + c4];
            L[row][c4 + 0] = v.x;
            L[row][c4 + 1] = v.y;
            L[row][c4 + 2] = v.z;
            L[row][c4 + 3] = v.w;
        }
    }
    __syncthreads();
    const int u = t >> 2, dg = t & 3;
    unsigned int hw[8];
#pragma unroll
    for (int j = 0; j < 8; ++j) {
        float x0 = L[(dg << 4) + (j << 1) + 0][u];
        float x1 = L[(dg << 4) + (j << 1) + 1][u];
        hw[j] = pack_f16(x0, x1);
    }
    size_t ob = (size_t)(u0v + u) * 512 + d0 + (dg << 4);
    *(uint4*)&T[ob]     = make_uint4(hw[0], hw[1], hw[2], hw[3]);
    *(uint4*)&T[ob + 8] = make_uint4(hw[4], hw[5], hw[6], hw[7]);
}

// ---------------------------------------------------------------------------
// Kernel 1 (grid 768, 128 thr = 2 waves): fp16 MFMA projections, no LDS,
// 8-deep register pipeline (128 stage VGPRs; no spill at (128,1)).
// Second half-loop issues NO prefetch (no dead wrap-around loads).
//   bid<512 : enc proj, rows=u cols=e. Epilogue: EH = exp2((d_enc+b)*2log2e)
//             fp16, u-packed-by-4.
//   bid>=512: dec proj, rows=q cols=u. Epilogue:
//             Gq4[b][q>>2][u][q&3] = exp2((dd+b)*2log2e) fp32 (q-packed).
// ---------------------------------------------------------------------------
__global__ __launch_bounds__(128, 1) void proj_kernel(
    const unsigned short* __restrict__ enc16, const unsigned short* __restrict__ dec16,
    const unsigned short* __restrict__ WeT,   const unsigned short* __restrict__ WdT,
    const float* __restrict__ bias_enc, const float* __restrict__ bias_dec,
    unsigned short* __restrict__ EH,   // [B][128][256][4] fp16
    float* __restrict__ Gq4)           // [B][32][512][4] fp32
{
    const float Cs = 2.8853900817779268f;   // 2*log2(e)
    const int bid = blockIdx.x;
    const int t = threadIdx.x;
    const int lane = t & 63, wr = t >> 6;    // wr: 32-row half of 64-row tile
    const int frow = lane & 15, quad = lane >> 4;
    const int ko = quad << 3;

    const unsigned short *pa0, *pa1, *pb0, *pb1;
    if (bid < 512) {
        const int b = bid & 7, s = bid >> 3;
        const int u0 = ((s & 7) << 6) + (wr << 5);   // 8 u-tiles of 64
        const int e0 = (s >> 3) << 5;                // 8 e-tiles of 32
        pa0 = WeT + (size_t)(u0 + frow) * 512 + ko;
        pa1 = pa0 + 16 * 512;
        pb0 = enc16 + (size_t)((b << 8) + e0 + frow) * 512 + ko;
        pb1 = pb0 + 16 * 512;
    } else {
        const int s = bid - 512;
        const int b = s & 7, s2 = s >> 3;
        const int q0 = ((s2 >> 4) << 6) + (wr << 5); // 2 q-tiles of 64
        const int u0 = (s2 & 15) << 5;               // 16 u-tiles of 32
        pa0 = dec16 + (size_t)((b << 7) + q0 + frow) * 512 + ko;
        pa1 = pa0 + 16 * 512;
        pb0 = WdT + (size_t)(u0 + frow) * 512 + ko;
        pb1 = pb0 + 16 * 512;
    }

    f16x8 sa0[8], sa1[8], sb0[8], sb1[8];
    auto LD = [&](int st, int k) {
        sa0[st] = *(const f16x8*)(pa0 + k);
        sa1[st] = *(const f16x8*)(pa1 + k);
        sb0[st] = *(const f16x8*)(pb0 + k);
        sb1[st] = *(const f16x8*)(pb1 + k);
    };
    f32x4 acc[2][2] = {{{0.f,0.f,0.f,0.f},{0.f,0.f,0.f,0.f}},
                       {{0.f,0.f,0.f,0.f},{0.f,0.f,0.f,0.f}}};
#pragma unroll
    for (int st = 0; st < 8; ++st) LD(st, st << 5);
#pragma unroll
    for (int st = 0; st < 8; ++st) {
        acc[0][0] = __builtin_amdgcn_mfma_f32_16x16x32_f16(sa0[st], sb0[st], acc[0][0], 0, 0, 0);
        acc[0][1] = __builtin_amdgcn_mfma_f32_16x16x32_f16(sa0[st], sb1[st], acc[0][1], 0, 0, 0);
        acc[1][0] = __builtin_amdgcn_mfma_f32_16x16x32_f16(sa1[st], sb0[st], acc[1][0], 0, 0, 0);
        acc[1][1] = __builtin_amdgcn_mfma_f32_16x16x32_f16(sa1[st], sb1[st], acc[1][1], 0, 0, 0);
        LD(st, 256 + (st << 5));             // prefetch second K-half
    }
#pragma unroll
    for (int st = 0; st < 8; ++st) {
        acc[0][0] = __builtin_amdgcn_mfma_f32_16x16x32_f16(sa0[st], sb0[st], acc[0][0], 0, 0, 0);
        acc[0][1] = __builtin_amdgcn_mfma_f32_16x16x32_f16(sa0[st], sb1[st], acc[0][1], 0, 0, 0);
        acc[1][0] = __builtin_amdgcn_mfma_f32_16x16x32_f16(sa1[st], sb0[st], acc[1][0], 0, 0, 0);
        acc[1][1] = __builtin_amdgcn_mfma_f32_16x16x32_f16(sa1[st], sb1[st], acc[1][1], 0, 0, 0);
    }

    // epilogue (C/D: col = lane&15 -> B-row, row = quad*4 + reg -> A-row)
    if (bid < 512) {
        const int b = bid & 7, s = bid >> 3;
        const int u0 = ((s & 7) << 6) + (wr << 5);
        const int e0 = (s >> 3) << 5;
#pragma unroll
        for (int fm = 0; fm < 2; ++fm)
#pragma unroll
            for (int fn = 0; fn < 2; ++fn) {
                int ub = u0 + (fm << 4) + (quad << 2);
                int e  = e0 + (fn << 4) + frow;
                float4 bi = *(const float4*)&bias_enc[ub];
                float E0 = __builtin_amdgcn_exp2f((acc[fm][fn][0] + bi.x) * Cs);
                float E1 = __builtin_amdgcn_exp2f((acc[fm][fn][1] + bi.y) * Cs);
                float E2 = __builtin_amdgcn_exp2f((acc[fm][fn][2] + bi.z) * Cs);
                float E3 = __builtin_amdgcn_exp2f((acc[fm][fn][3] + bi.w) * Cs);
                ((uint2*)EH)[(((size_t)(b << 7) + (ub >> 2)) << 8) + e] =
                    make_uint2(pack_f16(E0, E1), pack_f16(E2, E3));
            }
    } else {
        const int s = bid - 512;
        const int b = s & 7, s2 = s >> 3;
        const int q0 = ((s2 >> 4) << 6) + (wr << 5);
        const int u0 = (s2 & 15) << 5;
#pragma unroll
        for (int fm = 0; fm < 2; ++fm)
#pragma unroll
            for (int fn = 0; fn < 2; ++fn) {
                int qb = q0 + (fm << 4) + (quad << 2);   // multiple of 4
                int u  = u0 + (fn << 4) + frow;
                float bi = bias_dec[u];
                size_t base = (((size_t)(b << 5) + (qb >> 2)) << 11) + (u << 2);
#pragma unroll
                for (int g = 0; g < 4; ++g)
                    Gq4[base + g] =
                        __builtin_amdgcn_exp2f((acc[fm][fn][g] + bi) * Cs);
            }
    }
}

// ---------------------------------------------------------------------------
// Kernel 2 (grid 256, 1024 thr, q=4/block): scores -> softmax -> context.
// Score loop: 4-way rational combining (exact algebra):
//   sum_i w_i/X_i = [(w0*Y+w1*X)*ZW + (w2*W+w3*Z)*XY] * rcp(XY*ZW)
// -> 1 v_rcp per 4 u-terms.  q-columns as two f32x2 pairs (v_pk_fma_f32).
// Context reads enc16 fp16 (4 B/lane/iter: half the L2 traffic of fp32 —
// fp32 variant measured +2 us, L2-BW-bound).
// __launch_bounds__(1024,4): 128-reg cap, no spill.
// ---------------------------------------------------------------------------
__global__ __launch_bounds__(1024, 4) void attend_kernel(
    const unsigned short* __restrict__ enc16,  // [B,256,512] fp16
    const unsigned short* __restrict__ EH,     // [B][128][256][4] fp16
    const float* __restrict__ Gq4,             // [B][32][512][4] fp32
    const float* __restrict__ Wscore,          // [512]
    float* __restrict__ out)                   // [B, 128, 512]
{
    __shared__ float smem[8192];         // score accs 16 KB / ctx partials 32 KB
    __shared__ float wT[256][4];         // softmax weights [e][q]

    const float LOG2E = 1.4426950408889634f;

    const int bid = blockIdx.x;
    const int b = bid & 7;               // XCD-local batch
    const int qt = (bid >> 3) & 31;
    const int q0 = qt << 2;
    const int tid = threadIdx.x;
    const int wv = tid >> 6, lane = tid & 63;

    // ---------------- scores ----------------
    const int e  = ((wv & 3) << 6) + lane;
    const int uq = wv >> 2;
    const int u0 = __builtin_amdgcn_readfirstlane(uq << 7);   // SGPR-pinned

    const uint2* Ep = (const uint2*)EH + (((size_t)(b << 7) + (u0 >> 2)) << 8) + e;
    const float* Gq = Gq4 + (((size_t)(b << 5) + qt) << 11);  // [512][4]
    const float* Wp = Wscore + u0;

    f32x2 accLo = {0.f, 0.f}, accHi = {0.f, 0.f};
    uint2 de = Ep[0];
    float4 g0 = *(const float4*)(Gq + ((u0 + 0) << 2));
    float4 g1 = *(const float4*)(Gq + ((u0 + 1) << 2));
    float4 g2 = *(const float4*)(Gq + ((u0 + 2) << 2));
    float4 g3 = *(const float4*)(Gq + ((u0 + 3) << 2));
    float4 w4 = *(const float4*)(Wp);
    for (int g = 0; g < 32; ++g) {
        uint2 cde = de;
        float4 cg0 = g0, cg1 = g1, cg2 = g2, cg3 = g3, cw = w4;
        if (g < 31) {
            int un = u0 + ((g + 1) << 2);
            de = Ep[(size_t)(g + 1) << 8];
            g0 = *(const float4*)(Gq + ((un + 0) << 2));
            g1 = *(const float4*)(Gq + ((un + 1) << 2));
            g2 = *(const float4*)(Gq + ((un + 2) << 2));
            g3 = *(const float4*)(Gq + ((un + 3) << 2));
            w4 = *(const float4*)(Wp + ((g + 1) << 2));
        }
        float2 f01 = unpack_f16(cde.x);
        float2 f23 = unpack_f16(cde.y);
        const float E0 = f01.x, E1 = f01.y, E2 = f23.x, E3 = f23.y;
        // q-pair lo = (q0, q1)
        {
            f32x2 gl0 = {cg0.x, cg0.y}, gl1 = {cg1.x, cg1.y};
            f32x2 gl2 = {cg2.x, cg2.y}, gl3 = {cg3.x, cg3.y};
            f32x2 X = E0 * gl0 + 1.0f;
            f32x2 Y = E1 * gl1 + 1.0f;
            f32x2 Z = E2 * gl2 + 1.0f;
            f32x2 V = E3 * gl3 + 1.0f;
            f32x2 pxy = X * Y, pzw = Z * V;
            f32x2 den = pxy * pzw;
            f32x2 nxy = cw.x * Y + cw.y * X;
            f32x2 nzw = cw.z * V + cw.w * Z;
            f32x2 num = nxy * pzw + nzw * pxy;
            f32x2 r = { __builtin_amdgcn_rcpf(den.x),
                        __builtin_amdgcn_rcpf(den.y) };
            accLo += num * r;
        }
        // q-pair hi = (q2, q3)
        {
            f32x2 gh0 = {cg0.z, cg0.w}, gh1 = {cg1.z, cg1.w};
            f32x2 gh2 = {cg2.z, cg2.w}, gh3 = {cg3.z, cg3.w};
            f32x2 X = E0 * gh0 + 1.0f;
            f32x2 Y = E1 * gh1 + 1.0f;
            f32x2 Z = E2 * gh2 + 1.0f;
            f32x2 V = E3 * gh3 + 1.0f;
            f32x2 pxy = X * Y, pzw = Z * V;
            f32x2 den = pxy * pzw;
            f32x2 nxy = cw.x * Y + cw.y * X;
            f32x2 nzw = cw.z * V + cw.w * Z;
            f32x2 num = nxy * pzw + nzw * pxy;
            f32x2 r = { __builtin_amdgcn_rcpf(den.x),
                        __builtin_amdgcn_rcpf(den.y) };
            accHi += num * r;
        }
    }
    smem[((uq << 2) + 0) * 256 + e] = accLo.x;
    smem[((uq << 2) + 1) * 256 + e] = accLo.y;
    smem[((uq << 2) + 2) * 256 + e] = accHi.x;
    smem[((uq << 2) + 3) * 256 + e] = accHi.y;
    __syncthreads();

    // ---------------- softmax over e per q ----------------
    if (wv < 4) {
        const int q = wv;
        float l[4];
        float m = -1e30f;
#pragma unroll
        for (int i = 0; i < 4; ++i) {
            int ee = lane + (i << 6);
            float a = smem[(0 + q) * 256 + ee] + smem[(4 + q) * 256 + ee] +
                      smem[(8 + q) * 256 + ee] + smem[(12 + q) * 256 + ee];
            l[i] = -2.f * a;
            m = fmaxf(m, l[i]);
        }
#pragma unroll
        for (int mk = 32; mk >= 1; mk >>= 1) m = fmaxf(m, __shfl_xor(m, mk, 64));
        float p[4];
        float ssum = 0.f;
#pragma unroll
        for (int i = 0; i < 4; ++i) {
            p[i] = __builtin_amdgcn_exp2f((l[i] - m) * LOG2E);
            ssum += p[i];
        }
#pragma unroll
        for (int mk = 32; mk >= 1; mk >>= 1) ssum += __shfl_xor(ssum, mk, 64);
        float inv = __builtin_amdgcn_rcpf(ssum);
#pragma unroll
        for (int i = 0; i < 4; ++i) wT[lane + (i << 6)][q] = p[i] * inv;
    }
    __syncthreads();

    // ---------------- context (fp16 enc, 1x read, LDS reduce, pk-f32) ------
    {
        const int dp = tid & 255;                // d-pair index
        f32x2 p0 = {0.f, 0.f}, p1 = {0.f, 0.f};
        f32x2 p2 = {0.f, 0.f}, p3 = {0.f, 0.f};
        const unsigned int* ep = (const unsigned int*)enc16 +
                                 (((size_t)(b << 8) + (uq << 6)) << 8) + dp;
#pragma unroll 4
        for (int ee = 0; ee < 64; ++ee) {
            float2 xf = unpack_f16(ep[(size_t)ee << 8]);
            f32x2 x = {xf.x, xf.y};
            float4 w = *(const float4*)&wT[(uq << 6) + ee][0];   // wave-uniform
            p0 += w.x * x;
            p1 += w.y * x;
            p2 += w.z * x;
            p3 += w.w * x;
        }
        float2* sc = (float2*)smem;              // [16][256] float2 = 32 KB
        sc[((uq << 2) + 0) * 256 + dp] = make_float2(p0.x, p0.y);
        sc[((uq << 2) + 1) * 256 + dp] = make_float2(p1.x, p1.y);
        sc[((uq << 2) + 2) * 256 + dp] = make_float2(p2.x, p2.y);
        sc[((uq << 2) + 3) * 256 + dp] = make_float2(p3.x, p3.y);
        __syncthreads();
        const int q = tid >> 8;                  // 0..3
        float2 s0 = sc[(0 + q) * 256 + dp];
        float2 s1 = sc[(4 + q) * 256 + dp];
        float2 s2 = sc[(8 + q) * 256 + dp];
        float2 s3 = sc[(12 + q) * 256 + dp];
        float2 o = make_float2(s0.x + s1.x + s2.x + s3.x,
                               s0.y + s1.y + s2.y + s3.y);
        *(float2*)&out[(size_t)((b << 7) + q0 + q) * 512 + (dp << 1)] = o;
    }
}

// ---------------------------------------------------------------------------
extern "C" void kernel_launch(void* const* d_in, const int* in_sizes, int n_in,
                              void* d_out, int out_size, void* d_ws, size_t ws_size,
                              hipStream_t stream) {
    const float* enc      = (const float*)d_in[0];
    const float* dec      = (const float*)d_in[1];
    const float* Wenc     = (const float*)d_in[2];
    const float* Wdec     = (const float*)d_in[3];
    const float* Wscore   = (const float*)d_in[4];
    const float* bias_enc = (const float*)d_in[5];
    const float* bias_dec = (const float*)d_in[6];
    // d_in[7] = bias_score: constant shift, cancelled by softmax.
    float* out = (float*)d_out;

    float* ws = (float*)d_ws;
    unsigned short* EH  = (unsigned short*)ws;             // 2 MB  (1M fp16)
    float* Gq4          = ws + 524288;                     // 2 MB  (512K fp32)
    unsigned short* WeT = (unsigned short*)(ws + 1048576); // 512 KB
    unsigned short* WdT = WeT + 262144;                    // 512 KB
    unsigned short* enc16 = WdT + 262144;                  // 2 MB
    unsigned short* dec16 = enc16 + 1048576;               // 1 MB   (total 8 MB)

    prep_w<<<224, 256, 0, stream>>>(Wenc, Wdec, enc, dec, WeT, WdT, enc16, dec16);
    proj_kernel<<<768, 128, 0, stream>>>(enc16, dec16, WeT, WdT,
                                         bias_enc, bias_dec, EH, Gq4);
    attend_kernel<<<256, 1024, 0, stream>>>(enc16, EH, Gq4, Wscore, out);
}